// Round 1
// 368.887 us; speedup vs baseline: 1.0711x; 1.0711x over previous
//
#include <hip/hip_runtime.h>
#include <math.h>

#define B_ 256
#define L_ 50
#define H_ 128
#define N_ 100000
#define K_ 256  // 2H
#define NREP 64  // row-sum atomic replicas

typedef __attribute__((ext_vector_type(8))) short short8;   // 8 bf16 = 4 VGPR
typedef __attribute__((ext_vector_type(4))) float f32x4;

__device__ inline short f2bf(float x) {
  union { float f; unsigned u; } v; v.f = x;
  unsigned r = (v.u + 0x7fff + ((v.u >> 16) & 1)) >> 16;
  return (short)r;
}
__device__ inline float bf2f(short h) {
  union { unsigned u; float f; } v; v.u = ((unsigned)(unsigned short)h) << 16;
  return v.f;
}

// ---------------- Kernel A: attention + feat (bf16 hi/lo split, [B][K] layout) ----------------
__global__ __launch_bounds__(256)
void attn_feat_kernel(const float* __restrict__ am, const float* __restrict__ lm,
    const float* __restrict__ Ue_w, const float* __restrict__ Ue_b,
    const float* __restrict__ We_w, const float* __restrict__ We_b,
    const float* __restrict__ Ve_w, const float* __restrict__ Ve_b,
    const unsigned char* __restrict__ mask,
    short* __restrict__ feat_hi, short* __restrict__ feat_lo,
    float* __restrict__ sums_rep)
{
  const int b = blockIdx.x;
  const int t = threadIdx.x;  // 0..255
  __shared__ float UeS[H_ * H_];     // 64 KB, [h][k]
  __shared__ float amS[L_][H_];      // 25 KB
  __shared__ float lmS[H_], qS[H_];
  __shared__ float attnS[64];
  __shared__ float redW[4][32];      // per-wave score partials

  // zero this block's slice of the replicated row-sum accumulators (ws is poisoned)
  if (t < 64) sums_rep[b * 64 + t] = 0.0f;

  for (int i = t; i < H_ * H_ / 4; i += 256)
    ((float4*)UeS)[i] = ((const float4*)Ue_w)[i];
  for (int i = t; i < L_ * H_ / 4; i += 256)
    ((float4*)amS)[i] = ((const float4*)(am + (size_t)b * L_ * H_))[i];
  if (t < H_) lmS[t] = lm[b * H_ + t];
  __syncthreads();

  if (t < H_) {
    float q = We_b[t];
    #pragma unroll 8
    for (int h = 0; h < H_; ++h) q += lmS[h] * We_w[h * H_ + t];
    qS[t] = q;
  }
  __syncthreads();

  // scores: barrier-free main loop — wave-local reductions only
  const int k = t & 127, half = t >> 7, wv = t >> 6, lk = t & 63;
  const float ve  = Ve_w[k];
  const float ueb = Ue_b[k];
  const float veb = Ve_b[0];
  for (int li = 0; li < 25; ++li) {
    const int l = half * 25 + li;
    float a = ueb;
    #pragma unroll 8
    for (int h = 0; h < H_; ++h) a = fmaf(amS[l][h], UeS[h * H_ + k], a);
    float v = tanhf(a + qS[k]) * ve;
    #pragma unroll
    for (int off = 32; off > 0; off >>= 1) v += __shfl_down(v, off, 64);
    if (lk == 0) redW[wv][li] = v;
  }
  __syncthreads();
  if (t < 50) {
    const int hf = t / 25, li = t - hf * 25;
    attnS[t] = redW[hf * 2][li] + redW[hf * 2 + 1][li] + veb;
  }
  __syncthreads();

  if (t < 64) {
    float s = (t < L_) ? attnS[t] : -3.0e38f;
    if (t < L_ && mask[b * L_ + t]) s = -1.0e9f;
    float m = s;
    #pragma unroll
    for (int off = 32; off > 0; off >>= 1) m = fmaxf(m, __shfl_xor(m, off));
    float e = (t < L_) ? __expf(s - m) : 0.0f;
    float tot = e;
    #pragma unroll
    for (int off = 32; off > 0; off >>= 1) tot += __shfl_xor(tot, off);
    if (t < L_) attnS[t] = e / tot;
  }
  __syncthreads();

  if (t < H_) {
    float c = 0.0f;
    #pragma unroll
    for (int l = 0; l < L_; ++l) c = fmaf(attnS[l], amS[l][t], c);
    short h1 = f2bf(c);
    feat_hi[b * K_ + t] = h1;
    feat_lo[b * K_ + t] = f2bf(c - bf2f(h1));
    float lv = lmS[t];
    short h2 = f2bf(lv);
    feat_hi[b * K_ + H_ + t] = h2;
    feat_lo[b * K_ + H_ + t] = f2bf(lv - bf2f(h2));
  }
}

// ---------------- Kernel B: logits = feat @ Wexp via MFMA bf16x3 ----------------
// Block tile: M=256 (4 waves x 64 rows) x N=64. Wexp chunk (KC=64 rows) is
// reg-staged (16 coalesced dword loads/thread), converted ONCE per element to
// bf16 hi/lo (trunc-split), and written to LDS in [n][k] layout with a 16B-slot
// XOR swizzle (byte ^= (n&7)<<4) so stores AND fragment reads are conflict-free
// ds_{write,read}_b128. Raw lgkm-only barriers keep prefetch loads in flight
// across the buffer swap (no vmcnt(0) drain — the m97 structural stall).
#define TN 64
#define KC 64

__global__ __launch_bounds__(256)
void logits_mfma_kernel(const short* __restrict__ feat_hi, const short* __restrict__ feat_lo,
                        const float* __restrict__ Wexp, float* __restrict__ out,
                        float* __restrict__ sums_rep)
{
  // bf16 hi/lo B tiles, [n][k]: element (n,k) at byte n*128 + ((k*2) ^ ((n&7)<<4))
  __shared__ __align__(16) short bhS[2][TN * KC];   // 16 KB
  __shared__ __align__(16) short blS[2][TN * KC];   // 16 KB

  const int t = threadIdx.x;
  const int w = t >> 6;
  const int ln = t & 15, quad = (t >> 4) & 3;
  const int n0 = blockIdx.x * TN;
  const bool tail = (n0 + TN > N_);

  const int sn  = t & 63;          // staging column 0..63
  const int skb = (t >> 6) << 4;   // staging k base: 0,16,32,48
  const int ssx = (sn & 7) << 4;   // staging slot swizzle

  f32x4 acc[4][4];   // [mt][nt]
  #pragma unroll
  for (int i = 0; i < 4; ++i)
    #pragma unroll
    for (int j = 0; j < 4; ++j) acc[i][j] = (f32x4)(0.0f);

  float r[16];       // staged fp32 Wexp chunk slice (16 rows x 1 col)

  // LOADC: issue 16 coalesced global dword loads for chunk kc_ into r
  #define LOADC(kc_)                                                           \
    do {                                                                       \
      if (!tail) {                                                             \
        const float* g = Wexp + (size_t)((kc_) + skb) * N_ + n0 + sn;          \
        _Pragma("unroll")                                                      \
        for (int i = 0; i < 16; ++i) r[i] = g[(size_t)i * N_];                 \
      } else {                                                                 \
        const bool ok = (n0 + sn) < N_;                                        \
        const int gn = ok ? (n0 + sn) : (N_ - 1);  /* stay in bounds */        \
        const float* g = Wexp + (size_t)((kc_) + skb) * N_ + gn;               \
        _Pragma("unroll")                                                      \
        for (int i = 0; i < 16; ++i) { float v = g[(size_t)i * N_]; r[i] = ok ? v : 0.0f; } \
      }                                                                        \
    } while (0)

  // CONVW: convert r once -> bf16 hi (trunc) / lo (rounded residual), write swizzled
  #define CONVW(bufi)                                                          \
    do {                                                                       \
      short8 h2[2], l2[2];                                                     \
      _Pragma("unroll")                                                        \
      for (int c_ = 0; c_ < 2; ++c_) {                                         \
        _Pragma("unroll")                                                      \
        for (int j_ = 0; j_ < 8; ++j_) {                                       \
          union { float f; unsigned u; } v_; v_.f = r[c_ * 8 + j_];            \
          union { unsigned u; float f; } hv_; hv_.u = v_.u & 0xffff0000u;      \
          h2[c_][j_] = (short)(v_.u >> 16);                                    \
          l2[c_][j_] = f2bf(v_.f - hv_.f);                                     \
        }                                                                      \
      }                                                                        \
      char* ph_ = (char*)&bhS[bufi][0] + sn * 128;                             \
      char* pl_ = (char*)&blS[bufi][0] + sn * 128;                             \
      *(short8*)(ph_ + ((skb * 2)      ^ ssx)) = h2[0];                        \
      *(short8*)(ph_ + ((skb * 2 + 16) ^ ssx)) = h2[1];                        \
      *(short8*)(pl_ + ((skb * 2)      ^ ssx)) = l2[0];                        \
      *(short8*)(pl_ + ((skb * 2 + 16) ^ ssx)) = l2[1];                        \
    } while (0)

  // lgkm-only barrier: publishes ds_writes without draining vmcnt (prefetch stays in flight)
  #define LGKM_BARRIER() asm volatile("s_waitcnt lgkmcnt(0)\n\ts_barrier" ::: "memory")

  // prologue: stage chunk 0, publish, prefetch chunk 1
  LOADC(0);
  CONVW(0);
  LOADC(KC);
  LGKM_BARRIER();

  #pragma unroll
  for (int c = 0; c < K_ / KC; ++c) {
    const int cb = c & 1;
    const int kc = c * KC;

    #pragma unroll
    for (int kk = 0; kk < KC; kk += 32) {
      short8 ah[4], al[4];
      const int kof = kc + kk + quad * 8;
      #pragma unroll
      for (int mt = 0; mt < 4; ++mt) {
        const int m = w * 64 + mt * 16 + ln;
        ah[mt] = *(const short8*)(feat_hi + m * K_ + kof);
        al[mt] = *(const short8*)(feat_lo + m * K_ + kof);
      }
      short8 bh[4], bl[4];
      #pragma unroll
      for (int nt = 0; nt < 4; ++nt) {
        const int n = nt * 16 + ln;
        const int off = (kk * 2 + quad * 16) ^ ((n & 7) << 4);
        bh[nt] = *(const short8*)((const char*)&bhS[cb][0] + n * 128 + off);
        bl[nt] = *(const short8*)((const char*)&blS[cb][0] + n * 128 + off);
      }
      #pragma unroll
      for (int mt = 0; mt < 4; ++mt)
        #pragma unroll
        for (int nt = 0; nt < 4; ++nt) {
          acc[mt][nt] = __builtin_amdgcn_mfma_f32_16x16x32_bf16(ah[mt], bh[nt], acc[mt][nt], 0, 0, 0);
          acc[mt][nt] = __builtin_amdgcn_mfma_f32_16x16x32_bf16(ah[mt], bl[nt], acc[mt][nt], 0, 0, 0);
          acc[mt][nt] = __builtin_amdgcn_mfma_f32_16x16x32_bf16(al[mt], bh[nt], acc[mt][nt], 0, 0, 0);
        }
    }

    // convert+publish next chunk (loads issued one iteration ago -> latency covered
    // by the MFMA phase above), then prefetch chunk c+2
    if (c + 1 < K_ / KC) {
      CONVW((c + 1) & 1);
      if (c + 2 < K_ / KC) LOADC((c + 2) * KC);
      LGKM_BARRIER();
    }
  }

  // epilogue: exp, store, per-row sums (C/D: col = ln, row = quad*4 + reg)
  float rs[4][4];
  #pragma unroll
  for (int mt = 0; mt < 4; ++mt)
    #pragma unroll
    for (int r_ = 0; r_ < 4; ++r_) rs[mt][r_] = 0.0f;

  #pragma unroll
  for (int mt = 0; mt < 4; ++mt) {
    #pragma unroll
    for (int nt = 0; nt < 4; ++nt) {
      const int col = n0 + nt * 16 + ln;
      #pragma unroll
      for (int r_ = 0; r_ < 4; ++r_) {
        const int row = w * 64 + mt * 16 + quad * 4 + r_;
        const float e = __expf(acc[mt][nt][r_]);
        if (col < N_) {
          out[(size_t)row * N_ + col] = e;
          rs[mt][r_] += e;
        }
      }
    }
  }
  #pragma unroll
  for (int off = 8; off > 0; off >>= 1)
    #pragma unroll
    for (int mt = 0; mt < 4; ++mt)
      #pragma unroll
      for (int r_ = 0; r_ < 4; ++r_) rs[mt][r_] += __shfl_down(rs[mt][r_], off, 16);
  if (ln == 0) {
    float* rep = sums_rep + (blockIdx.x & (NREP - 1)) * 256;
    #pragma unroll
    for (int mt = 0; mt < 4; ++mt)
      #pragma unroll
      for (int r_ = 0; r_ < 4; ++r_)
        atomicAdd(&rep[w * 64 + mt * 16 + quad * 4 + r_], rs[mt][r_]);
  }
}

// ---------------- Kernel B2: fold the 64 replicas into sums ----------------
__global__ __launch_bounds__(256)
void reduce_sums_kernel(const float* __restrict__ sums_rep, float* __restrict__ sums)
{
  const int b = threadIdx.x;   // one thread per row, single block
  float s = 0.0f;
  #pragma unroll
  for (int r = 0; r < NREP; ++r) s += sums_rep[r * 256 + b];
  sums[b] = s;
}

// ---------------- Kernel C: explore mask ----------------
__global__ __launch_bounds__(256)
void mask_kernel(const int* __restrict__ seq, float* __restrict__ out, float* __restrict__ sums)
{
  int idx = blockIdx.x * 256 + threadIdx.x;   // B*L = 12800
  if (idx >= B_ * L_) return;
  int b = idx / L_;
  int item = seq[idx];
  if (item > 0) {
    float old = atomicExch(&out[(size_t)b * N_ + item], 0.0f);
    if (old != 0.0f) atomicAdd(&sums[b], -old);   // 256 addresses, <=50 ops each: fine
  }
}

// ---------------- Kernel D: normalize (2D grid, no div, 4 float4/thread) ----------------
#define NV4 (N_ / 4)   // 25000 float4 per row
__global__ __launch_bounds__(256)
void norm_kernel(float* __restrict__ out, const float* __restrict__ sums)
{
  const int b = blockIdx.y;
  const float inv = 1.0f / sums[b];
  float4* row = (float4*)(out + (size_t)b * N_);
  const int i0 = blockIdx.x * (256 * 4) + threadIdx.x;
  #pragma unroll
  for (int u = 0; u < 4; ++u) {
    const int i = i0 + u * 256;
    if (i < NV4) {
      float4 v = row[i];
      v.x *= inv; v.y *= inv; v.z *= inv; v.w *= inv;
      row[i] = v;
    }
  }
}

extern "C" void kernel_launch(void* const* d_in, const int* in_sizes, int n_in,
                              void* d_out, int out_size, void* d_ws, size_t ws_size,
                              hipStream_t stream)
{
  const float* am   = (const float*)d_in[0];
  const float* lm   = (const float*)d_in[1];
  const int*   seq  = (const int*)d_in[2];
  const unsigned char* mask = (const unsigned char*)d_in[3];
  const float* Ue_w = (const float*)d_in[4];
  const float* Ue_b = (const float*)d_in[5];
  const float* We_w = (const float*)d_in[6];
  const float* We_b = (const float*)d_in[7];
  const float* Ve_w = (const float*)d_in[8];
  const float* Ve_b = (const float*)d_in[9];
  const float* Wexp = (const float*)d_in[10];
  float* out = (float*)d_out;

  short* feat_hi  = (short*)d_ws;                     // 128 KB
  short* feat_lo  = feat_hi + B_ * K_;                // 128 KB
  float* sums_rep = (float*)(feat_lo + B_ * K_);      // 64*256 floats = 64 KB
  float* sums     = sums_rep + NREP * 256;            // 256 floats

  attn_feat_kernel<<<B_, 256, 0, stream>>>(am, lm, Ue_w, Ue_b, We_w, We_b,
                                           Ve_w, Ve_b, mask, feat_hi, feat_lo, sums_rep);
  logits_mfma_kernel<<<(N_ + TN - 1) / TN, 256, 0, stream>>>(feat_hi, feat_lo, Wexp, out, sums_rep);
  reduce_sums_kernel<<<1, 256, 0, stream>>>(sums_rep, sums);
  mask_kernel<<<(B_ * L_ + 255) / 256, 256, 0, stream>>>(seq, out, sums);
  dim3 gN((NV4 + 256 * 4 - 1) / (256 * 4), B_);
  norm_kernel<<<gN, 256, 0, stream>>>(out, sums);
}